// Round 1
// baseline (28.238 us; speedup 1.0000x reference)
//
#include <hip/hip_runtime.h>

// Problem: fake_parameter [2048,20000] f32, input [2048,20000] f32.
// b = (param * (input>0)) > 0.5  -> binary
// out = 1.0 at the first 64 ones of each row (top_k tie-break = lowest index), else 0.
//
// Memory-optimal structure: writes dominate (164 MB out vs ~17 MB needed reads,
// since the 64th one occurs ~col 256 on average). One block per row; block-wide
// prefix count of ones; once 64 ones seen, remaining chunks are store-only.

#define ROWS 2048
#define COLS 20000
#define KSEL 64
#define THR 0.5f

__global__ __launch_bounds__(256) void fake_profile_kernel(
    const float* __restrict__ param,
    const float* __restrict__ input,
    float* __restrict__ out)
{
    const int row  = blockIdx.x;
    const int tid  = threadIdx.x;
    const int lane = tid & 63;
    const int wave = tid >> 6;

    const float4* p4 = reinterpret_cast<const float4*>(param + (size_t)row * COLS);
    const float4* i4 = reinterpret_cast<const float4*>(input + (size_t)row * COLS);
    float4*       o4 = reinterpret_cast<float4*>(out + (size_t)row * COLS);

    const int n4 = COLS / 4;  // 5000 float4 per row (row base is 16B-aligned: 20000*4 % 16 == 0)

    __shared__ int wsum[4];

    int base = 0;  // block-uniform running count of ones seen in previous chunks

    for (int c0 = 0; c0 < n4; c0 += 256) {
        const int idx    = c0 + tid;
        const bool active = (idx < n4);

        if (base >= KSEL) {
            // Fast path: everything past the 64th one is zero. Stores only.
            if (active) {
                o4[idx] = make_float4(0.f, 0.f, 0.f, 0.f);
            }
            continue;
        }

        // Full path: load, binarize, block-wide exclusive prefix of ones.
        int b0 = 0, b1 = 0, b2 = 0, b3 = 0;
        if (active) {
            const float4 pv = p4[idx];
            const float4 iv = i4[idx];
            b0 = (iv.x > 0.f) && (pv.x > THR);
            b1 = (iv.y > 0.f) && (pv.y > THR);
            b2 = (iv.z > 0.f) && (pv.z > THR);
            b3 = (iv.w > 0.f) && (pv.w > THR);
        }
        const int t = b0 + b1 + b2 + b3;

        // wave (64-lane) inclusive scan
        int incl = t;
        #pragma unroll
        for (int d = 1; d < 64; d <<= 1) {
            int v = __shfl_up(incl, d, 64);
            if (lane >= d) incl += v;
        }
        if (lane == 63) wsum[wave] = incl;
        __syncthreads();

        int woff = 0;
        #pragma unroll
        for (int w = 0; w < 4; ++w)
            if (w < wave) woff += wsum[w];
        const int total = wsum[0] + wsum[1] + wsum[2] + wsum[3];

        int r = base + woff + (incl - t);  // exclusive rank of this thread's first element
        if (active) {
            float4 o;
            o.x = (b0 && r < KSEL) ? 1.f : 0.f; r += b0;
            o.y = (b1 && r < KSEL) ? 1.f : 0.f; r += b1;
            o.z = (b2 && r < KSEL) ? 1.f : 0.f; r += b2;
            o.w = (b3 && r < KSEL) ? 1.f : 0.f; r += b3;
            o4[idx] = o;
        }

        base += total;
        __syncthreads();  // protect wsum before next chunk's writes
    }
}

extern "C" void kernel_launch(void* const* d_in, const int* in_sizes, int n_in,
                              void* d_out, int out_size, void* d_ws, size_t ws_size,
                              hipStream_t stream) {
    const float* param = (const float*)d_in[0];
    const float* input = (const float*)d_in[1];
    float* out = (float*)d_out;
    fake_profile_kernel<<<ROWS, 256, 0, stream>>>(param, input, out);
}